// Round 2
// baseline (3339.941 us; speedup 1.0000x reference)
//
#include <hip/hip_runtime.h>
#include <cstddef>
#include <cstdint>

// ---------------- problem constants ----------------
#define BB   4
#define CC   256
#define HHh  128
#define WWi  256
#define HW   32768      // H*W
#define CHW  8388608    // C*H*W
#define NN   131072     // B*H*W
#define KK   19
#define MMp  10
#define RR   190        // K*M
#define RP   192

// ---------------- output offsets (floats) ----------------
#define O_LOG   2490368     // out_seg size = 4*19*128*256
#define O_TGT   27394048
#define O_PROTO 27525120

// ---------------- ws offsets (floats) ----------------
#define WS_BUF   0           // 33,554,432 : y -> z1 -> _c (in-place, [b][c][h][w] layout)
#define WS_WT    33554432    // 589,824 : conv_w transposed [ic*9+t9][oc]
#define WS_PAT   34144256    // 65,536 : pa_w^T [c][o]
#define WS_PBT   34209792    // 65,536 : pb_w^T [c][o]
#define WS_PN    34275328    // 48,640 : normalized protos [190][256]
#define WS_PNT   34323968    // 49,152 : PnT [256][192]
#define WS_T     34373120    // 3*192 sinkhorn sums
#define WS_F     34373696    // 48,640 : f accumulator
#define WS_A     34422336    // 3*192 sinkhorn row scales
#define WS_NCNT  34422912    // 192 int
#define WS_CORR  34423104    // 131,072 int
#define WS_KEY   34554176    // 131,072 int
// end = 34,685,248 floats = 138.7 MB

// ============ prototype normalize ============
__global__ __launch_bounds__(256) void k_prep_protos(const float* __restrict__ protos,
                                                     float* __restrict__ Pn,
                                                     float* __restrict__ PnT) {
  int r = blockIdx.x, d = threadIdx.x;
  if (r >= RR) { PnT[d * RP + r] = 0.f; return; }  // zero pad cols 190,191
  float v = protos[r * 256 + d];
  __shared__ float red[256];
  red[d] = v * v;
  __syncthreads();
  #pragma unroll
  for (int s = 128; s > 0; s >>= 1) {
    if (d < s) red[d] += red[d + s];
    __syncthreads();
  }
  float inv = 1.f / fmaxf(sqrtf(red[0]), 1e-12f);
  float pv = v * inv;
  Pn[r * 256 + d] = pv;
  PnT[d * RP + r] = pv;
}

// ============ weight transposes (coalesced consumption later) ============
__global__ __launch_bounds__(256) void k_transpose_w(const float* __restrict__ conv_w,
                                                     const float* __restrict__ pa_w,
                                                     const float* __restrict__ pb_w,
                                                     float* __restrict__ wT,
                                                     float* __restrict__ paT,
                                                     float* __restrict__ pbT) {
  int blk = blockIdx.x, t = threadIdx.x;
  if (blk < 2304) {                       // blk = ic*9 + t9
    int ic = blk / 9, t9 = blk - ic * 9;
    wT[blk * 256 + t] = conv_w[(t * 256 + ic) * 9 + t9];
  } else if (blk < 2560) {
    int c = blk - 2304;
    paT[c * 256 + t] = pa_w[t * 256 + c];
  } else {
    int c = blk - 2560;
    pbT[c * 256 + t] = pb_w[t * 256 + c];
  }
}

// ============ conv3x3 + bias + bn1 + relu ============
// grid (1024, 2): x = pt (wt,h,b), y = oc-tile of 128. tile = 128 px * 128 oc.
__global__ __launch_bounds__(256) void k_conv(const float* __restrict__ x,
                                              const float* __restrict__ wT,
                                              const float* __restrict__ conv_b,
                                              const float* __restrict__ bn_s,
                                              const float* __restrict__ bn_b,
                                              const float* __restrict__ bn_m,
                                              const float* __restrict__ bn_v,
                                              float* __restrict__ y) {
  int pt = blockIdx.x;
  int wt = pt & 1, h = (pt >> 1) & 127, b = pt >> 8;
  int oc0 = blockIdx.y * 128;
  int w0 = wt * 128;
  int tid = threadIdx.x, tx = tid & 15, ty = tid >> 4;
  __shared__ float xs[8][3][136];     // 130 used per row
  __shared__ float ws2[8][9][128];
  float acc[8][8];
  #pragma unroll
  for (int j = 0; j < 8; j++)
    #pragma unroll
    for (int i = 0; i < 8; i++) acc[j][i] = 0.f;

  const float* xb = x + (size_t)b * CHW;
  for (int ic0 = 0; ic0 < 256; ic0 += 8) {
    for (int idx = tid; idx < 3264; idx += 256) {
      int kc = idx / 408, rem = idx - kc * 408;
      int r = rem / 136, wl = rem - r * 136;
      int hh = h - 1 + r, wg = w0 - 1 + wl;
      float v = 0.f;
      if (wl < 130 && (unsigned)hh < 128u && (unsigned)wg < 256u)
        v = xb[(ic0 + kc) * HW + hh * WWi + wg];
      xs[kc][r][wl] = v;
    }
    // ws2[8][9][128] has 1152 elements per kc (NOT pow2): decompose exactly.
    for (int idx = tid; idx < 9216; idx += 256) {
      int oc = idx & 127;
      int rest = idx >> 7;          // [0,72) = kc*9 + t9
      int kc = rest / 9;
      int t9 = rest - kc * 9;
      ws2[kc][t9][oc] = wT[((ic0 + kc) * 9 + t9) * 256 + oc0 + oc];
    }
    __syncthreads();
    #pragma unroll
    for (int kc = 0; kc < 8; kc++) {
      #pragma unroll
      for (int kh = 0; kh < 3; kh++) {
        float xv[12];
        const float4* xp = (const float4*)&xs[kc][kh][tx * 8];
        float4 x0 = xp[0], x1 = xp[1], x2 = xp[2];
        xv[0]=x0.x; xv[1]=x0.y; xv[2]=x0.z; xv[3]=x0.w;
        xv[4]=x1.x; xv[5]=x1.y; xv[6]=x1.z; xv[7]=x1.w;
        xv[8]=x2.x; xv[9]=x2.y; xv[10]=x2.z; xv[11]=x2.w;
        #pragma unroll
        for (int kw = 0; kw < 3; kw++) {
          const float4* wp = (const float4*)&ws2[kc][kh * 3 + kw][ty * 8];
          float4 wa = wp[0], wb = wp[1];
          float wr[8] = {wa.x, wa.y, wa.z, wa.w, wb.x, wb.y, wb.z, wb.w};
          #pragma unroll
          for (int j = 0; j < 8; j++)
            #pragma unroll
            for (int i = 0; i < 8; i++)
              acc[j][i] = fmaf(wr[j], xv[kw + i], acc[j][i]);
        }
      }
    }
    __syncthreads();
  }
  float* yb = y + (size_t)b * CHW + (size_t)h * WWi + w0 + tx * 8;
  #pragma unroll
  for (int j = 0; j < 8; j++) {
    int oc = oc0 + ty * 8 + j;
    float sc = bn_s[oc] / sqrtf(bn_v[oc] + 1e-5f);
    float sh = (conv_b[oc] - bn_m[oc]) * sc + bn_b[oc];
    float4 o0, o1;
    o0.x = fmaxf(acc[j][0] * sc + sh, 0.f);
    o0.y = fmaxf(acc[j][1] * sc + sh, 0.f);
    o0.z = fmaxf(acc[j][2] * sc + sh, 0.f);
    o0.w = fmaxf(acc[j][3] * sc + sh, 0.f);
    o1.x = fmaxf(acc[j][4] * sc + sh, 0.f);
    o1.y = fmaxf(acc[j][5] * sc + sh, 0.f);
    o1.z = fmaxf(acc[j][6] * sc + sh, 0.f);
    o1.w = fmaxf(acc[j][7] * sc + sh, 0.f);
    float* yp = yb + (size_t)oc * HW;
    ((float4*)yp)[0] = o0;
    ((float4*)yp)[1] = o1;
  }
}

// ============ 1x1-conv stages, in-place (full 256 oc per 64-px tile) ============
// MODE 0: z1 = relu(bn2(pa_w@y + pa_b));  p0..p3 = bn2 s,b,m,v
// MODE 1: _c = l2n(ln(l2n(pb_w@z1 + pb_b), fn_g, fn_b)); p0,p1 = fn_g,fn_b
template <int MODE>
__global__ __launch_bounds__(256) void k_mlp(float* __restrict__ buf,
                                             const float* __restrict__ wTr,
                                             const float* __restrict__ bias,
                                             const float* __restrict__ p0,
                                             const float* __restrict__ p1,
                                             const float* __restrict__ p2,
                                             const float* __restrict__ p3) {
  int bid = blockIdx.x;
  int b = bid >> 9, hw0 = (bid & 511) * 64;
  int tid = threadIdx.x, tx = tid & 15, ty = tid >> 4;
  __shared__ float xsS[8][68];
  __shared__ float wsS[8][256];
  __shared__ float redS[2][16][16][4];
  float acc[16][4];
  #pragma unroll
  for (int o = 0; o < 16; o++)
    #pragma unroll
    for (int i = 0; i < 4; i++) acc[o][i] = 0.f;

  float* src = buf + (size_t)b * CHW + hw0;
  for (int c0 = 0; c0 < 256; c0 += 8) {
    for (int idx = tid; idx < 512; idx += 256) {
      int kc = idx >> 6, px = idx & 63;
      xsS[kc][px] = src[(size_t)(c0 + kc) * HW + px];
    }
    for (int idx = tid; idx < 2048; idx += 256) {
      int kc = idx >> 8, oc = idx & 255;
      wsS[kc][oc] = wTr[(c0 + kc) * 256 + oc];
    }
    __syncthreads();
    #pragma unroll
    for (int kc = 0; kc < 8; kc++) {
      float4 xv = *(const float4*)&xsS[kc][tx * 4];
      float xr[4] = {xv.x, xv.y, xv.z, xv.w};
      #pragma unroll
      for (int q = 0; q < 4; q++) {
        float4 wv = *(const float4*)&wsS[kc][ty * 16 + q * 4];
        float wr[4] = {wv.x, wv.y, wv.z, wv.w};
        #pragma unroll
        for (int jo = 0; jo < 4; jo++)
          #pragma unroll
          for (int i = 0; i < 4; i++)
            acc[q * 4 + jo][i] = fmaf(wr[jo], xr[i], acc[q * 4 + jo][i]);
      }
    }
    __syncthreads();
  }

  if (MODE == 0) {
    #pragma unroll
    for (int o = 0; o < 16; o++) {
      int oc = ty * 16 + o;
      float sc = p0[oc] / sqrtf(p3[oc] + 1e-5f);
      float sh = (bias[oc] - p2[oc]) * sc + p1[oc];
      float4 ov;
      ov.x = fmaxf(acc[o][0] * sc + sh, 0.f);
      ov.y = fmaxf(acc[o][1] * sc + sh, 0.f);
      ov.z = fmaxf(acc[o][2] * sc + sh, 0.f);
      ov.w = fmaxf(acc[o][3] * sc + sh, 0.f);
      *(float4*)&buf[(size_t)b * CHW + (size_t)oc * HW + hw0 + tx * 4] = ov;
    }
  } else {
    // z in acc + bias ; per-pixel stats over the 256 channels (16 ty-groups)
    float s1[4] = {0, 0, 0, 0}, s2[4] = {0, 0, 0, 0};
    #pragma unroll
    for (int o = 0; o < 16; o++) {
      float bz = bias[ty * 16 + o];
      #pragma unroll
      for (int i = 0; i < 4; i++) {
        float z = acc[o][i] + bz;
        acc[o][i] = z;
        s1[i] += z;
        s2[i] += z * z;
      }
    }
    #pragma unroll
    for (int i = 0; i < 4; i++) { redS[0][ty][tx][i] = s1[i]; redS[1][ty][tx][i] = s2[i]; }
    __syncthreads();
    #pragma unroll
    for (int s = 8; s > 0; s >>= 1) {
      if (ty < s) {
        #pragma unroll
        for (int i = 0; i < 4; i++) {
          redS[0][ty][tx][i] += redS[0][ty + s][tx][i];
          redS[1][ty][tx][i] += redS[1][ty + s][tx][i];
        }
      }
      __syncthreads();
    }
    float invn[4], muu[4], rq[4];
    #pragma unroll
    for (int i = 0; i < 4; i++) {
      float S1 = redS[0][0][tx][i], S2 = redS[1][0][tx][i];
      float iv = 1.f / fmaxf(sqrtf(S2), 1e-12f);        // l2n guard
      float mu = S1 * iv * (1.f / 256.f);
      float eu2 = S2 * iv * iv * (1.f / 256.f);
      float var = fmaxf(eu2 - mu * mu, 0.f);
      invn[i] = iv; muu[i] = mu; rq[i] = 1.f / sqrtf(var + 1e-5f);
    }
    __syncthreads();
    float s3[4] = {0, 0, 0, 0};
    #pragma unroll
    for (int o = 0; o < 16; o++) {
      int oc = ty * 16 + o;
      float g = p0[oc], bt = p1[oc];
      #pragma unroll
      for (int i = 0; i < 4; i++) {
        float v = (acc[o][i] * invn[i] - muu[i]) * rq[i] * g + bt;
        acc[o][i] = v;
        s3[i] += v * v;
      }
    }
    #pragma unroll
    for (int i = 0; i < 4; i++) redS[0][ty][tx][i] = s3[i];
    __syncthreads();
    #pragma unroll
    for (int s = 8; s > 0; s >>= 1) {
      if (ty < s) {
        #pragma unroll
        for (int i = 0; i < 4; i++) redS[0][ty][tx][i] += redS[0][ty + s][tx][i];
      }
      __syncthreads();
    }
    float cinv[4];
    #pragma unroll
    for (int i = 0; i < 4; i++)
      cinv[i] = 1.f / fmaxf(sqrtf(redS[0][0][tx][i]), 1e-12f);
    #pragma unroll
    for (int o = 0; o < 16; o++) {
      int oc = ty * 16 + o;
      float4 ov;
      ov.x = acc[o][0] * cinv[0];
      ov.y = acc[o][1] * cinv[1];
      ov.z = acc[o][2] * cinv[2];
      ov.w = acc[o][3] * cinv[3];
      *(float4*)&buf[(size_t)b * CHW + (size_t)oc * HW + hw0 + tx * 4] = ov;
    }
  }
}

// ============ masks / proto_logits GEMM: _c[64px] x PnT -> logits[n][190] ============
__global__ __launch_bounds__(256) void k_masks(const float* __restrict__ cbuf,
                                               const float* __restrict__ PnT,
                                               float* __restrict__ logits) {
  int pt = blockIdx.x;
  int b = pt >> 9, hw0 = (pt & 511) * 64;
  int r0 = blockIdx.y * 64;
  int tid = threadIdx.x, tx = tid & 15, ty = tid >> 4;
  __shared__ float xsS[16][68];
  __shared__ float wsS[16][64];
  float acc[4][4];
  #pragma unroll
  for (int j = 0; j < 4; j++)
    #pragma unroll
    for (int i = 0; i < 4; i++) acc[j][i] = 0.f;

  const float* src = cbuf + (size_t)b * CHW + hw0;
  for (int c0 = 0; c0 < 256; c0 += 16) {
    for (int idx = tid; idx < 1024; idx += 256) {
      int kc = idx >> 6, px = idx & 63;
      xsS[kc][px] = src[(size_t)(c0 + kc) * HW + px];
    }
    for (int idx = tid; idx < 1024; idx += 256) {
      int kc = idx >> 6, r = idx & 63;
      wsS[kc][r] = PnT[(c0 + kc) * RP + r0 + r];
    }
    __syncthreads();
    #pragma unroll
    for (int kc = 0; kc < 16; kc++) {
      float4 xv = *(const float4*)&xsS[kc][tx * 4];
      float4 wv = *(const float4*)&wsS[kc][ty * 4];
      float xr[4] = {xv.x, xv.y, xv.z, xv.w};
      float wr[4] = {wv.x, wv.y, wv.z, wv.w};
      #pragma unroll
      for (int j = 0; j < 4; j++)
        #pragma unroll
        for (int i = 0; i < 4; i++)
          acc[j][i] = fmaf(wr[j], xr[i], acc[j][i]);
    }
    __syncthreads();
  }
  int n0 = b * HW + hw0 + tx * 4;
  #pragma unroll
  for (int j = 0; j < 4; j++) {
    int r = r0 + ty * 4 + j;
    if (r < RR) {
      #pragma unroll
      for (int i = 0; i < 4; i++)
        logits[(size_t)(n0 + i) * RR + r] = acc[j][i];
    }
  }
}

// ============ out_seg = LN_k(max_j masks) + pred/correct ============
__global__ __launch_bounds__(256) void k_out(const float* __restrict__ logits,
                                             const int* __restrict__ gt,
                                             const float* __restrict__ mn_g,
                                             const float* __restrict__ mn_b,
                                             float* __restrict__ out_seg,
                                             int* __restrict__ corr) {
  __shared__ float lds[64][193];
  int n0 = blockIdx.x * 64;
  int tid = threadIdx.x;
  for (int idx = tid; idx < 64 * RR; idx += 256) {
    int rr = idx / RR, cc = idx - rr * RR;
    lds[rr][cc] = logits[(size_t)n0 * RR + idx];
  }
  __syncthreads();
  if (tid < 64) {
    int n = n0 + tid;
    float mx[KK];
    float S1 = 0.f, S2 = 0.f;
    #pragma unroll
    for (int k = 0; k < KK; k++) {
      float m_ = lds[tid][k * 10];
      #pragma unroll
      for (int j = 1; j < 10; j++) m_ = fmaxf(m_, lds[tid][k * 10 + j]);
      mx[k] = m_;
      S1 += m_;
      S2 += m_ * m_;
    }
    float mu = S1 * (1.f / 19.f);
    float var = fmaxf(S2 * (1.f / 19.f) - mu * mu, 0.f);
    float inv = 1.f / sqrtf(var + 1e-5f);
    int b = n >> 15, hw = n & 32767;
    float best = -3.4e38f;
    int pred = 0;
    #pragma unroll
    for (int k = 0; k < KK; k++) {
      float o = (mx[k] - mu) * inv * mn_g[k] + mn_b[k];
      out_seg[(size_t)b * 622592 + (size_t)k * 32768 + hw] = o;
      if (o > best) { best = o; pred = k; }
    }
    corr[n] = (gt[n] == pred) ? 1 : 0;
  }
}

// ============ sinkhorn reduction pass: T[k*10+j] += E * b(aprev) ============
__global__ __launch_bounds__(256) void k_sink_sum(const float* __restrict__ logits,
                                                  const int* __restrict__ gt,
                                                  float* __restrict__ Tout,
                                                  const float* __restrict__ aprev) {
  __shared__ float tl[RP];
  int tid = threadIdx.x;
  if (tid < RP) tl[tid] = 0.f;
  __syncthreads();
  int n = blockIdx.x * 256 + tid;
  int k = gt[n];
  const float* lp = logits + (size_t)n * RR + k * 10;
  float e[10];
  #pragma unroll
  for (int j = 0; j < 10; j++) e[j] = expf(lp[j] * 20.0f);
  float bfac = 1.f;
  if (aprev != nullptr) {
    float den = 0.f;
    #pragma unroll
    for (int j = 0; j < 10; j++) den += e[j] * aprev[k * 10 + j];
    bfac = 1.f / fmaxf(den, 1e-30f);
  }
  #pragma unroll
  for (int j = 0; j < 10; j++) atomicAdd(&tl[k * 10 + j], e[j] * bfac);
  __syncthreads();
  if (tid < RR) atomicAdd(&Tout[tid], tl[tid]);
}

__global__ __launch_bounds__(256) void k_calc_a(const float* __restrict__ T,
                                                float* __restrict__ a) {
  int t = threadIdx.x;
  if (t < RR) a[t] = 1.f / (10.f * fmaxf(T[t], 1e-12f));
  else if (t < RP) a[t] = 0.f;
}

// ============ final sinkhorn pass: proto_target, gumbel-hard key, n_cnt ============
__global__ __launch_bounds__(256) void k_final(const float* __restrict__ logits,
                                               const int* __restrict__ gt,
                                               const float* __restrict__ a3,
                                               const float* __restrict__ gu,
                                               const int* __restrict__ corr,
                                               float* __restrict__ tgt,
                                               int* __restrict__ key,
                                               int* __restrict__ ncnt) {
  int n = blockIdx.x * 256 + threadIdx.x;
  int k = gt[n];
  const float* lp = logits + (size_t)n * RR + k * 10;
  float w[10];
  float den = 0.f, bestw = -1.f;
  int idx = 0;
  #pragma unroll
  for (int j = 0; j < 10; j++) {
    w[j] = expf(lp[j] * 20.0f) * a3[k * 10 + j];
    den += w[j];
    if (w[j] > bestw) { bestw = w[j]; idx = j; }
  }
  tgt[n] = (float)(idx + 10 * k);
  float dinv = 1.f / fmaxf(den, 1e-30f);
  const float* gp = gu + ((size_t)k * NN + n) * 10;
  float bestq = -3.4e38f;
  int jh = 0;
  #pragma unroll
  for (int j = 0; j < 10; j++) {
    float g = -logf(-logf(gp[j] + 1e-20f) + 1e-20f);
    float q = w[j] * dinv + g;
    if (q > bestq) { bestq = q; jh = j; }
  }
  int kv = -1;
  if (corr[n]) {
    kv = k * 10 + jh;
    atomicAdd(&ncnt[kv], 1);
  }
  key[n] = kv;
}

// ============ f[k,j,:] += _c[n,:] over counted samples ============
__global__ __launch_bounds__(256) void k_accum_f(const int* __restrict__ key,
                                                 const float* __restrict__ cbuf,
                                                 float* __restrict__ f) {
  __shared__ int ks[64];
  int n0 = blockIdx.x * 64;
  int tid = threadIdx.x;
  if (tid < 64) ks[tid] = key[n0 + tid];
  __syncthreads();
  for (int s = 0; s < 64; s++) {
    int kv = ks[s];
    if (kv >= 0) {
      int n = n0 + s;
      int b = n >> 15, hw = n & 32767;
      atomicAdd(&f[kv * 256 + tid], cbuf[(size_t)b * CHW + (size_t)tid * HW + hw]);
    }
  }
}

// ============ prototype EMA update + renormalize ============
__global__ __launch_bounds__(256) void k_update(const float* __restrict__ Pn,
                                                const float* __restrict__ f,
                                                const int* __restrict__ ncnt,
                                                float* __restrict__ outP) {
  int r = blockIdx.x, d = threadIdx.x;
  int k = r / 10;
  __shared__ float red[256];
  __shared__ int hasS;
  if (d == 0) {
    int s = 0;
    for (int j = 0; j < 10; j++) s += ncnt[k * 10 + j];
    hasS = s;
  }
  __syncthreads();
  bool upd = (ncnt[r] != 0) && (hasS > 0);
  float fv = f[r * 256 + d];
  red[d] = fv * fv;
  __syncthreads();
  #pragma unroll
  for (int s = 128; s > 0; s >>= 1) {
    if (d < s) red[d] += red[d + s];
    __syncthreads();
  }
  float fn2 = red[0];
  __syncthreads();
  float fl = fv / fmaxf(sqrtf(fn2), 1e-12f);
  float p = Pn[r * 256 + d];
  float nv = upd ? (0.999f * p + 0.001f * fl) : p;
  red[d] = nv * nv;
  __syncthreads();
  #pragma unroll
  for (int s = 128; s > 0; s >>= 1) {
    if (d < s) red[d] += red[d + s];
    __syncthreads();
  }
  outP[r * 256 + d] = nv / fmaxf(sqrtf(red[0]), 1e-12f);
}

// ============ launch ============
extern "C" void kernel_launch(void* const* d_in, const int* in_sizes, int n_in,
                              void* d_out, int out_size, void* d_ws, size_t ws_size,
                              hipStream_t stream) {
  const float* x      = (const float*)d_in[0];
  const int*   gt     = (const int*)  d_in[1];
  const float* gu     = (const float*)d_in[2];
  const float* conv_w = (const float*)d_in[3];
  const float* conv_b = (const float*)d_in[4];
  const float* bn1_s  = (const float*)d_in[5];
  const float* bn1_b  = (const float*)d_in[6];
  const float* bn1_m  = (const float*)d_in[7];
  const float* bn1_v  = (const float*)d_in[8];
  const float* pa_w   = (const float*)d_in[9];
  const float* pa_b   = (const float*)d_in[10];
  const float* bn2_s  = (const float*)d_in[11];
  const float* bn2_b  = (const float*)d_in[12];
  const float* bn2_m  = (const float*)d_in[13];
  const float* bn2_v  = (const float*)d_in[14];
  const float* pb_w   = (const float*)d_in[15];
  const float* pb_b   = (const float*)d_in[16];
  const float* fn_g   = (const float*)d_in[17];
  const float* fn_b   = (const float*)d_in[18];
  const float* mn_g   = (const float*)d_in[19];
  const float* mn_b   = (const float*)d_in[20];
  const float* protos = (const float*)d_in[21];

  float* ws  = (float*)d_ws;
  float* out = (float*)d_out;

  float* buf  = ws + WS_BUF;
  float* wT   = ws + WS_WT;
  float* paT  = ws + WS_PAT;
  float* pbT  = ws + WS_PBT;
  float* Pn   = ws + WS_PN;
  float* PnT  = ws + WS_PNT;
  float* Tarr = ws + WS_T;
  float* farr = ws + WS_F;
  float* aarr = ws + WS_A;
  int*   ncnt = (int*)(ws + WS_NCNT);
  int*   corr = (int*)(ws + WS_CORR);
  int*   key  = (int*)(ws + WS_KEY);

  float* logits = out + O_LOG;

  // zero T[3*192] + f[48640] + a[3*192] + ncnt[192]  (contiguous region)
  hipMemsetAsync(ws + WS_T, 0, (size_t)(576 + 48640 + 576 + 192) * 4, stream);

  k_prep_protos<<<RP, 256, 0, stream>>>(protos, Pn, PnT);
  k_transpose_w<<<2816, 256, 0, stream>>>(conv_w, pa_w, pb_w, wT, paT, pbT);
  k_conv<<<dim3(1024, 2), 256, 0, stream>>>(x, wT, conv_b, bn1_s, bn1_b, bn1_m, bn1_v, buf);
  k_mlp<0><<<2048, 256, 0, stream>>>(buf, paT, pa_b, bn2_s, bn2_b, bn2_m, bn2_v);
  k_mlp<1><<<2048, 256, 0, stream>>>(buf, pbT, pb_b, fn_g, fn_b, nullptr, nullptr);
  k_masks<<<dim3(2048, 3), 256, 0, stream>>>(buf, PnT, logits);
  k_out<<<2048, 256, 0, stream>>>(logits, gt, mn_g, mn_b, out, corr);
  k_sink_sum<<<512, 256, 0, stream>>>(logits, gt, Tarr + 0,   nullptr);
  k_calc_a<<<1, 256, 0, stream>>>(Tarr + 0,   aarr + 0);
  k_sink_sum<<<512, 256, 0, stream>>>(logits, gt, Tarr + 192, aarr + 0);
  k_calc_a<<<1, 256, 0, stream>>>(Tarr + 192, aarr + 192);
  k_sink_sum<<<512, 256, 0, stream>>>(logits, gt, Tarr + 384, aarr + 192);
  k_calc_a<<<1, 256, 0, stream>>>(Tarr + 384, aarr + 384);
  k_final<<<512, 256, 0, stream>>>(logits, gt, aarr + 384, gu, corr, out + O_TGT, key, ncnt);
  k_accum_f<<<2048, 256, 0, stream>>>(key, buf, farr);
  k_update<<<190, 256, 0, stream>>>(Pn, farr, ncnt, out + O_PROTO);

  (void)in_sizes; (void)n_in; (void)out_size; (void)ws_size;
}

// Round 3
// 2082.783 us; speedup vs baseline: 1.6036x; 1.6036x over previous
//
#include <hip/hip_runtime.h>
#include <cstddef>
#include <cstdint>

// ---------------- problem constants ----------------
#define BB   4
#define CC   256
#define HHh  128
#define WWi  256
#define HW   32768      // H*W
#define CHW  8388608    // C*H*W
#define NN   131072     // B*H*W
#define KK   19
#define MMp  10
#define RR   190        // K*M
#define RP   192

// ---------------- output offsets (floats) ----------------
#define O_LOG   2490368     // out_seg size = 4*19*128*256
#define O_TGT   27394048
#define O_PROTO 27525120

// ---------------- ws offsets (floats) ----------------
#define WS_BUF   0           // 33,554,432 : y -> z1 -> _c (in-place, [b][c][h][w] layout)
#define WS_WPK   33554432    // 663,552 floats: wpk_h + wpk_l, each 9*8*256*36 shorts
#define WS_PAT   34217984    // 65,536 : pa_w^T [c][o]
#define WS_PBT   34283520    // 65,536 : pb_w^T [c][o]
#define WS_PN    34349056    // 48,640 : normalized protos [190][256]
#define WS_PNT   34397696    // 49,152 : PnT [256][192]
#define WS_T     34446848    // 3*192 sinkhorn sums
#define WS_F     34447424    // 48,640 : f accumulator
#define WS_A     34496064    // 3*192 sinkhorn row scales
#define WS_NCNT  34496640    // 192 int
#define WS_CORR  34496832    // 131,072 int
#define WS_KEY   34627904    // 131,072 int
// end = 34,758,976 floats = 139.0 MB

typedef __attribute__((ext_vector_type(8))) short bf16x8;
typedef __attribute__((ext_vector_type(4))) short s16x4;
typedef __attribute__((ext_vector_type(4))) float f32x4;

// split fp32 v into bf16 hi (truncate) + bf16 lo (truncate of residual)
__device__ __forceinline__ void split2pack(float v0, float v1, unsigned& hp, unsigned& lp) {
  unsigned u0 = __float_as_uint(v0), u1 = __float_as_uint(v1);
  unsigned h0 = u0 & 0xffff0000u, h1 = u1 & 0xffff0000u;
  float r0 = v0 - __uint_as_float(h0);
  float r1 = v1 - __uint_as_float(h1);
  hp = (h0 >> 16) | h1;
  lp = (__float_as_uint(r0) >> 16) | (__float_as_uint(r1) & 0xffff0000u);
}

__device__ __forceinline__ void split1(float v, short& h, short& l) {
  unsigned u = __float_as_uint(v);
  unsigned hm = u & 0xffff0000u;
  float r = v - __uint_as_float(hm);
  h = (short)(hm >> 16);
  l = (short)(__float_as_uint(r) >> 16);
}

__device__ __forceinline__ bf16x8 ldfrag(const short* p) {
  union { bf16x8 v; s16x4 q[2]; } u;
  u.q[0] = *(const s16x4*)p;
  u.q[1] = *(const s16x4*)(p + 4);
  return u.v;
}

// ============ prototype normalize ============
__global__ __launch_bounds__(256) void k_prep_protos(const float* __restrict__ protos,
                                                     float* __restrict__ Pn,
                                                     float* __restrict__ PnT) {
  int r = blockIdx.x, d = threadIdx.x;
  if (r >= RR) { PnT[d * RP + r] = 0.f; return; }  // zero pad cols 190,191
  float v = protos[r * 256 + d];
  __shared__ float red[256];
  red[d] = v * v;
  __syncthreads();
  #pragma unroll
  for (int s = 128; s > 0; s >>= 1) {
    if (d < s) red[d] += red[d + s];
    __syncthreads();
  }
  float inv = 1.f / fmaxf(sqrtf(red[0]), 1e-12f);
  float pv = v * inv;
  Pn[r * 256 + d] = pv;
  PnT[d * RP + r] = pv;
}

// ============ conv weight split-pack prepass ============
// wpk[t9][icb][oc][36] bf16 (32 real ic + 4 pad), h and l arrays.
__global__ __launch_bounds__(256) void k_prep_wsplit(const float* __restrict__ conv_w,
                                                     short* __restrict__ wpk_h,
                                                     short* __restrict__ wpk_l) {
  int blk = blockIdx.x;             // t9*8 + icb
  int t9 = blk >> 3, icb = blk & 7;
  int oc = threadIdx.x;
  short* dh = wpk_h + ((size_t)blk * 256 + oc) * 36;
  short* dl = wpk_l + ((size_t)blk * 256 + oc) * 36;
  #pragma unroll 4
  for (int i = 0; i < 32; i++) {
    float v = conv_w[((size_t)oc * 256 + icb * 32 + i) * 9 + t9];
    short h, l;
    split1(v, h, l);
    dh[i] = h; dl[i] = l;
  }
  #pragma unroll
  for (int i = 32; i < 36; i++) { dh[i] = 0; dl[i] = 0; }
}

// ============ 1x1 weight transposes ============
__global__ __launch_bounds__(256) void k_transpose_w(const float* __restrict__ pa_w,
                                                     const float* __restrict__ pb_w,
                                                     float* __restrict__ paT,
                                                     float* __restrict__ pbT) {
  int blk = blockIdx.x, t = threadIdx.x;
  if (blk < 256) {
    paT[blk * 256 + t] = pa_w[t * 256 + blk];
  } else {
    int c = blk - 256;
    pbT[c * 256 + t] = pb_w[t * 256 + c];
  }
}

// ============ conv3x3 + bias + bn1 + relu : bf16x2-split MFMA ============
// grid (1024, 2): x = (wt,h,b), y = oc-tile of 128. block tile = 128 px * 128 oc.
// 4 waves = 2M x 2N; wave tile 64px x 64oc = 4x4 frags of 16x16, K-step 32.
__global__ __launch_bounds__(256) void k_conv_mfma(const float* __restrict__ x,
                                                   const short* __restrict__ wpk_h,
                                                   const short* __restrict__ wpk_l,
                                                   const float* __restrict__ conv_b,
                                                   const float* __restrict__ bn_s,
                                                   const float* __restrict__ bn_b,
                                                   const float* __restrict__ bn_m,
                                                   const float* __restrict__ bn_v,
                                                   float* __restrict__ y) {
  int pt = blockIdx.x;
  int wt = pt & 1, h = (pt >> 1) & 127, b = pt >> 8;
  int oc0 = blockIdx.y * 128;
  int w0 = wt * 128;
  int tid = threadIdx.x;
  int lane = tid & 63, wv = tid >> 6;
  int wm = wv & 1, wn = wv >> 1;
  int l15 = lane & 15, l4 = lane >> 4;
  int wlb = wm * 64 + l15;          // A-row base within tile
  int ocb = wn * 64 + l15;          // B-col base within tile

  __shared__ short xt_h[3 * 130 * 36];
  __shared__ short xt_l[3 * 130 * 36];
  __shared__ short wt_h[128 * 36];
  __shared__ short wt_l[128 * 36];

  f32x4 acc[4][4];
  #pragma unroll
  for (int i = 0; i < 4; i++)
    #pragma unroll
    for (int j = 0; j < 4; j++) acc[i][j] = (f32x4){0.f, 0.f, 0.f, 0.f};

  const float* xb = x + (size_t)b * CHW;

  #pragma unroll 1
  for (int ic0 = 0; ic0 < 256; ic0 += 32) {
    int icb = ic0 >> 5;
    // ---- stage A: 3 rows x 130 wl x 16 ic-pairs, split h/l ----
    #pragma unroll 1
    for (int idx = tid; idx < 3 * 16 * 130; idx += 256) {
      int wl = idx % 130;
      int rest = idx / 130;             // kh*16 + ip
      int kh = rest >> 4, ip = rest & 15;
      int hh = h - 1 + kh, wg = w0 - 1 + wl;
      float v0 = 0.f, v1 = 0.f;
      if ((unsigned)hh < 128u && (unsigned)wg < 256u) {
        const float* px = xb + (size_t)(ic0 + 2 * ip) * HW + hh * WWi + wg;
        v0 = px[0]; v1 = px[HW];
      }
      unsigned hp, lp;
      split2pack(v0, v1, hp, lp);
      int off = (kh * 130 + wl) * 36 + 2 * ip;    // even short index
      *(unsigned*)&xt_h[off] = hp;
      *(unsigned*)&xt_l[off] = lp;
    }
    // ---- 9 taps ----
    #pragma unroll 1
    for (int t9 = 0; t9 < 9; ++t9) {
      int kh = (t9 * 11) >> 5;          // t9/3
      int kw = t9 - kh * 3;
      {   // stage B: linear copy 128 oc x 36 (h and l)
        const unsigned* sh_ = (const unsigned*)(wpk_h + (((size_t)t9 * 8 + icb) * 256 + oc0) * 36);
        const unsigned* sl_ = (const unsigned*)(wpk_l + (((size_t)t9 * 8 + icb) * 256 + oc0) * 36);
        unsigned* dh_ = (unsigned*)wt_h;
        unsigned* dl_ = (unsigned*)wt_l;
        #pragma unroll 1
        for (int idx = tid; idx < 2304; idx += 256) { dh_[idx] = sh_[idx]; dl_[idx] = sl_[idx]; }
      }
      __syncthreads();
      bf16x8 ah[4], al[4], bh4[4], bl4[4];
      #pragma unroll
      for (int nf = 0; nf < 4; ++nf) {
        int off = (ocb + nf * 16) * 36 + l4 * 8;
        bh4[nf] = ldfrag(wt_h + off);
        bl4[nf] = ldfrag(wt_l + off);
      }
      #pragma unroll
      for (int mf = 0; mf < 4; ++mf) {
        int off = (kh * 130 + wlb + mf * 16 + kw) * 36 + l4 * 8;
        ah[mf] = ldfrag(xt_h + off);
        al[mf] = ldfrag(xt_l + off);
      }
      #pragma unroll
      for (int mf = 0; mf < 4; ++mf)
        #pragma unroll
        for (int nf = 0; nf < 4; ++nf) {
          acc[mf][nf] = __builtin_amdgcn_mfma_f32_16x16x32_bf16(ah[mf], bh4[nf], acc[mf][nf], 0, 0, 0);
          acc[mf][nf] = __builtin_amdgcn_mfma_f32_16x16x32_bf16(ah[mf], bl4[nf], acc[mf][nf], 0, 0, 0);
          acc[mf][nf] = __builtin_amdgcn_mfma_f32_16x16x32_bf16(al[mf], bh4[nf], acc[mf][nf], 0, 0, 0);
        }
      __syncthreads();
    }
  }
  // ---- epilogue: BN + ReLU, store f32x4 along w ----
  float* yb = y + (size_t)b * CHW + (size_t)h * WWi + w0;
  #pragma unroll
  for (int nf = 0; nf < 4; ++nf) {
    int oc = oc0 + ocb + nf * 16;
    float sc = bn_s[oc] / sqrtf(bn_v[oc] + 1e-5f);
    float sh = (conv_b[oc] - bn_m[oc]) * sc + bn_b[oc];
    #pragma unroll
    for (int mf = 0; mf < 4; ++mf) {
      int w = wm * 64 + mf * 16 + l4 * 4;
      float4 o;
      o.x = fmaxf(acc[mf][nf][0] * sc + sh, 0.f);
      o.y = fmaxf(acc[mf][nf][1] * sc + sh, 0.f);
      o.z = fmaxf(acc[mf][nf][2] * sc + sh, 0.f);
      o.w = fmaxf(acc[mf][nf][3] * sc + sh, 0.f);
      *(float4*)&yb[(size_t)oc * HW + w] = o;
    }
  }
}

// ============ 1x1-conv stages, in-place (full 256 oc per 64-px tile) ============
// MODE 0: z1 = relu(bn2(pa_w@y + pa_b));  p0..p3 = bn2 s,b,m,v
// MODE 1: _c = l2n(ln(l2n(pb_w@z1 + pb_b), fn_g, fn_b)); p0,p1 = fn_g,fn_b
template <int MODE>
__global__ __launch_bounds__(256) void k_mlp(float* __restrict__ buf,
                                             const float* __restrict__ wTr,
                                             const float* __restrict__ bias,
                                             const float* __restrict__ p0,
                                             const float* __restrict__ p1,
                                             const float* __restrict__ p2,
                                             const float* __restrict__ p3) {
  int bid = blockIdx.x;
  int b = bid >> 9, hw0 = (bid & 511) * 64;
  int tid = threadIdx.x, tx = tid & 15, ty = tid >> 4;
  __shared__ float xsS[8][68];
  __shared__ float wsS[8][256];
  __shared__ float redS[2][16][16][4];
  float acc[16][4];
  #pragma unroll
  for (int o = 0; o < 16; o++)
    #pragma unroll
    for (int i = 0; i < 4; i++) acc[o][i] = 0.f;

  float* src = buf + (size_t)b * CHW + hw0;
  for (int c0 = 0; c0 < 256; c0 += 8) {
    for (int idx = tid; idx < 512; idx += 256) {
      int kc = idx >> 6, px = idx & 63;
      xsS[kc][px] = src[(size_t)(c0 + kc) * HW + px];
    }
    for (int idx = tid; idx < 2048; idx += 256) {
      int kc = idx >> 8, oc = idx & 255;
      wsS[kc][oc] = wTr[(c0 + kc) * 256 + oc];
    }
    __syncthreads();
    #pragma unroll
    for (int kc = 0; kc < 8; kc++) {
      float4 xv = *(const float4*)&xsS[kc][tx * 4];
      float xr[4] = {xv.x, xv.y, xv.z, xv.w};
      #pragma unroll
      for (int q = 0; q < 4; q++) {
        float4 wv = *(const float4*)&wsS[kc][ty * 16 + q * 4];
        float wr[4] = {wv.x, wv.y, wv.z, wv.w};
        #pragma unroll
        for (int jo = 0; jo < 4; jo++)
          #pragma unroll
          for (int i = 0; i < 4; i++)
            acc[q * 4 + jo][i] = fmaf(wr[jo], xr[i], acc[q * 4 + jo][i]);
      }
    }
    __syncthreads();
  }

  if (MODE == 0) {
    #pragma unroll
    for (int o = 0; o < 16; o++) {
      int oc = ty * 16 + o;
      float sc = p0[oc] / sqrtf(p3[oc] + 1e-5f);
      float sh = (bias[oc] - p2[oc]) * sc + p1[oc];
      float4 ov;
      ov.x = fmaxf(acc[o][0] * sc + sh, 0.f);
      ov.y = fmaxf(acc[o][1] * sc + sh, 0.f);
      ov.z = fmaxf(acc[o][2] * sc + sh, 0.f);
      ov.w = fmaxf(acc[o][3] * sc + sh, 0.f);
      *(float4*)&buf[(size_t)b * CHW + (size_t)oc * HW + hw0 + tx * 4] = ov;
    }
  } else {
    float s1[4] = {0, 0, 0, 0}, s2[4] = {0, 0, 0, 0};
    #pragma unroll
    for (int o = 0; o < 16; o++) {
      float bz = bias[ty * 16 + o];
      #pragma unroll
      for (int i = 0; i < 4; i++) {
        float z = acc[o][i] + bz;
        acc[o][i] = z;
        s1[i] += z;
        s2[i] += z * z;
      }
    }
    #pragma unroll
    for (int i = 0; i < 4; i++) { redS[0][ty][tx][i] = s1[i]; redS[1][ty][tx][i] = s2[i]; }
    __syncthreads();
    #pragma unroll
    for (int s = 8; s > 0; s >>= 1) {
      if (ty < s) {
        #pragma unroll
        for (int i = 0; i < 4; i++) {
          redS[0][ty][tx][i] += redS[0][ty + s][tx][i];
          redS[1][ty][tx][i] += redS[1][ty + s][tx][i];
        }
      }
      __syncthreads();
    }
    float invn[4], muu[4], rq[4];
    #pragma unroll
    for (int i = 0; i < 4; i++) {
      float S1 = redS[0][0][tx][i], S2 = redS[1][0][tx][i];
      float iv = 1.f / fmaxf(sqrtf(S2), 1e-12f);
      float mu = S1 * iv * (1.f / 256.f);
      float eu2 = S2 * iv * iv * (1.f / 256.f);
      float var = fmaxf(eu2 - mu * mu, 0.f);
      invn[i] = iv; muu[i] = mu; rq[i] = 1.f / sqrtf(var + 1e-5f);
    }
    __syncthreads();
    float s3[4] = {0, 0, 0, 0};
    #pragma unroll
    for (int o = 0; o < 16; o++) {
      int oc = ty * 16 + o;
      float g = p0[oc], bt = p1[oc];
      #pragma unroll
      for (int i = 0; i < 4; i++) {
        float v = (acc[o][i] * invn[i] - muu[i]) * rq[i] * g + bt;
        acc[o][i] = v;
        s3[i] += v * v;
      }
    }
    #pragma unroll
    for (int i = 0; i < 4; i++) redS[0][ty][tx][i] = s3[i];
    __syncthreads();
    #pragma unroll
    for (int s = 8; s > 0; s >>= 1) {
      if (ty < s) {
        #pragma unroll
        for (int i = 0; i < 4; i++) redS[0][ty][tx][i] += redS[0][ty + s][tx][i];
      }
      __syncthreads();
    }
    float cinv[4];
    #pragma unroll
    for (int i = 0; i < 4; i++)
      cinv[i] = 1.f / fmaxf(sqrtf(redS[0][0][tx][i]), 1e-12f);
    #pragma unroll
    for (int o = 0; o < 16; o++) {
      int oc = ty * 16 + o;
      float4 ov;
      ov.x = acc[o][0] * cinv[0];
      ov.y = acc[o][1] * cinv[1];
      ov.z = acc[o][2] * cinv[2];
      ov.w = acc[o][3] * cinv[3];
      *(float4*)&buf[(size_t)b * CHW + (size_t)oc * HW + hw0 + tx * 4] = ov;
    }
  }
}

// ============ masks / proto_logits GEMM: _c[64px] x PnT -> logits[n][190] ============
__global__ __launch_bounds__(256) void k_masks(const float* __restrict__ cbuf,
                                               const float* __restrict__ PnT,
                                               float* __restrict__ logits) {
  int pt = blockIdx.x;
  int b = pt >> 9, hw0 = (pt & 511) * 64;
  int r0 = blockIdx.y * 64;
  int tid = threadIdx.x, tx = tid & 15, ty = tid >> 4;
  __shared__ float xsS[16][68];
  __shared__ float wsS[16][64];
  float acc[4][4];
  #pragma unroll
  for (int j = 0; j < 4; j++)
    #pragma unroll
    for (int i = 0; i < 4; i++) acc[j][i] = 0.f;

  const float* src = cbuf + (size_t)b * CHW + hw0;
  for (int c0 = 0; c0 < 256; c0 += 16) {
    for (int idx = tid; idx < 1024; idx += 256) {
      int kc = idx >> 6, px = idx & 63;
      xsS[kc][px] = src[(size_t)(c0 + kc) * HW + px];
    }
    for (int idx = tid; idx < 1024; idx += 256) {
      int kc = idx >> 6, r = idx & 63;
      wsS[kc][r] = PnT[(c0 + kc) * RP + r0 + r];
    }
    __syncthreads();
    #pragma unroll
    for (int kc = 0; kc < 16; kc++) {
      float4 xv = *(const float4*)&xsS[kc][tx * 4];
      float4 wv = *(const float4*)&wsS[kc][ty * 4];
      float xr[4] = {xv.x, xv.y, xv.z, xv.w};
      float wr[4] = {wv.x, wv.y, wv.z, wv.w};
      #pragma unroll
      for (int j = 0; j < 4; j++)
        #pragma unroll
        for (int i = 0; i < 4; i++)
          acc[j][i] = fmaf(wr[j], xr[i], acc[j][i]);
    }
    __syncthreads();
  }
  int n0 = b * HW + hw0 + tx * 4;
  #pragma unroll
  for (int j = 0; j < 4; j++) {
    int r = r0 + ty * 4 + j;
    if (r < RR) {
      #pragma unroll
      for (int i = 0; i < 4; i++)
        logits[(size_t)(n0 + i) * RR + r] = acc[j][i];
    }
  }
}

// ============ out_seg = LN_k(max_j masks) + pred/correct ============
__global__ __launch_bounds__(256) void k_out(const float* __restrict__ logits,
                                             const int* __restrict__ gt,
                                             const float* __restrict__ mn_g,
                                             const float* __restrict__ mn_b,
                                             float* __restrict__ out_seg,
                                             int* __restrict__ corr) {
  __shared__ float lds[64][193];
  int n0 = blockIdx.x * 64;
  int tid = threadIdx.x;
  for (int idx = tid; idx < 64 * RR; idx += 256) {
    int rr = idx / RR, cc = idx - rr * RR;
    lds[rr][cc] = logits[(size_t)n0 * RR + idx];
  }
  __syncthreads();
  if (tid < 64) {
    int n = n0 + tid;
    float mx[KK];
    float S1 = 0.f, S2 = 0.f;
    #pragma unroll
    for (int k = 0; k < KK; k++) {
      float m_ = lds[tid][k * 10];
      #pragma unroll
      for (int j = 1; j < 10; j++) m_ = fmaxf(m_, lds[tid][k * 10 + j]);
      mx[k] = m_;
      S1 += m_;
      S2 += m_ * m_;
    }
    float mu = S1 * (1.f / 19.f);
    float var = fmaxf(S2 * (1.f / 19.f) - mu * mu, 0.f);
    float inv = 1.f / sqrtf(var + 1e-5f);
    int b = n >> 15, hw = n & 32767;
    float best = -3.4e38f;
    int pred = 0;
    #pragma unroll
    for (int k = 0; k < KK; k++) {
      float o = (mx[k] - mu) * inv * mn_g[k] + mn_b[k];
      out_seg[(size_t)b * 622592 + (size_t)k * 32768 + hw] = o;
      if (o > best) { best = o; pred = k; }
    }
    corr[n] = (gt[n] == pred) ? 1 : 0;
  }
}

// ============ sinkhorn reduction pass: T[k*10+j] += E * b(aprev) ============
__global__ __launch_bounds__(256) void k_sink_sum(const float* __restrict__ logits,
                                                  const int* __restrict__ gt,
                                                  float* __restrict__ Tout,
                                                  const float* __restrict__ aprev) {
  __shared__ float tl[RP];
  int tid = threadIdx.x;
  if (tid < RP) tl[tid] = 0.f;
  __syncthreads();
  int n = blockIdx.x * 256 + tid;
  int k = gt[n];
  const float* lp = logits + (size_t)n * RR + k * 10;
  float e[10];
  #pragma unroll
  for (int j = 0; j < 10; j++) e[j] = expf(lp[j] * 20.0f);
  float bfac = 1.f;
  if (aprev != nullptr) {
    float den = 0.f;
    #pragma unroll
    for (int j = 0; j < 10; j++) den += e[j] * aprev[k * 10 + j];
    bfac = 1.f / fmaxf(den, 1e-30f);
  }
  #pragma unroll
  for (int j = 0; j < 10; j++) atomicAdd(&tl[k * 10 + j], e[j] * bfac);
  __syncthreads();
  if (tid < RR) atomicAdd(&Tout[tid], tl[tid]);
}

__global__ __launch_bounds__(256) void k_calc_a(const float* __restrict__ T,
                                                float* __restrict__ a) {
  int t = threadIdx.x;
  if (t < RR) a[t] = 1.f / (10.f * fmaxf(T[t], 1e-12f));
  else if (t < RP) a[t] = 0.f;
}

// ============ final sinkhorn pass: proto_target, gumbel-hard key, n_cnt ============
__global__ __launch_bounds__(256) void k_final(const float* __restrict__ logits,
                                               const int* __restrict__ gt,
                                               const float* __restrict__ a3,
                                               const float* __restrict__ gu,
                                               const int* __restrict__ corr,
                                               float* __restrict__ tgt,
                                               int* __restrict__ key,
                                               int* __restrict__ ncnt) {
  int n = blockIdx.x * 256 + threadIdx.x;
  int k = gt[n];
  const float* lp = logits + (size_t)n * RR + k * 10;
  float w[10];
  float den = 0.f, bestw = -1.f;
  int idx = 0;
  #pragma unroll
  for (int j = 0; j < 10; j++) {
    w[j] = expf(lp[j] * 20.0f) * a3[k * 10 + j];
    den += w[j];
    if (w[j] > bestw) { bestw = w[j]; idx = j; }
  }
  tgt[n] = (float)(idx + 10 * k);
  float dinv = 1.f / fmaxf(den, 1e-30f);
  const float* gp = gu + ((size_t)k * NN + n) * 10;
  float bestq = -3.4e38f;
  int jh = 0;
  #pragma unroll
  for (int j = 0; j < 10; j++) {
    float g = -logf(-logf(gp[j] + 1e-20f) + 1e-20f);
    float q = w[j] * dinv + g;
    if (q > bestq) { bestq = q; jh = j; }
  }
  int kv = -1;
  if (corr[n]) {
    kv = k * 10 + jh;
    atomicAdd(&ncnt[kv], 1);
  }
  key[n] = kv;
}

// ============ f[k,j,:] += _c[n,:] over counted samples ============
__global__ __launch_bounds__(256) void k_accum_f(const int* __restrict__ key,
                                                 const float* __restrict__ cbuf,
                                                 float* __restrict__ f) {
  __shared__ int ks[64];
  int n0 = blockIdx.x * 64;
  int tid = threadIdx.x;
  if (tid < 64) ks[tid] = key[n0 + tid];
  __syncthreads();
  for (int s = 0; s < 64; s++) {
    int kv = ks[s];
    if (kv >= 0) {
      int n = n0 + s;
      int b = n >> 15, hw = n & 32767;
      atomicAdd(&f[kv * 256 + tid], cbuf[(size_t)b * CHW + (size_t)tid * HW + hw]);
    }
  }
}

// ============ prototype EMA update + renormalize ============
__global__ __launch_bounds__(256) void k_update(const float* __restrict__ Pn,
                                                const float* __restrict__ f,
                                                const int* __restrict__ ncnt,
                                                float* __restrict__ outP) {
  int r = blockIdx.x, d = threadIdx.x;
  int k = r / 10;
  __shared__ float red[256];
  __shared__ int hasS;
  if (d == 0) {
    int s = 0;
    for (int j = 0; j < 10; j++) s += ncnt[k * 10 + j];
    hasS = s;
  }
  __syncthreads();
  bool upd = (ncnt[r] != 0) && (hasS > 0);
  float fv = f[r * 256 + d];
  red[d] = fv * fv;
  __syncthreads();
  #pragma unroll
  for (int s = 128; s > 0; s >>= 1) {
    if (d < s) red[d] += red[d + s];
    __syncthreads();
  }
  float fn2 = red[0];
  __syncthreads();
  float fl = fv / fmaxf(sqrtf(fn2), 1e-12f);
  float p = Pn[r * 256 + d];
  float nv = upd ? (0.999f * p + 0.001f * fl) : p;
  red[d] = nv * nv;
  __syncthreads();
  #pragma unroll
  for (int s = 128; s > 0; s >>= 1) {
    if (d < s) red[d] += red[d + s];
    __syncthreads();
  }
  outP[r * 256 + d] = nv / fmaxf(sqrtf(red[0]), 1e-12f);
}

// ============ launch ============
extern "C" void kernel_launch(void* const* d_in, const int* in_sizes, int n_in,
                              void* d_out, int out_size, void* d_ws, size_t ws_size,
                              hipStream_t stream) {
  const float* x      = (const float*)d_in[0];
  const int*   gt     = (const int*)  d_in[1];
  const float* gu     = (const float*)d_in[2];
  const float* conv_w = (const float*)d_in[3];
  const float* conv_b = (const float*)d_in[4];
  const float* bn1_s  = (const float*)d_in[5];
  const float* bn1_b  = (const float*)d_in[6];
  const float* bn1_m  = (const float*)d_in[7];
  const float* bn1_v  = (const float*)d_in[8];
  const float* pa_w   = (const float*)d_in[9];
  const float* pa_b   = (const float*)d_in[10];
  const float* bn2_s  = (const float*)d_in[11];
  const float* bn2_b  = (const float*)d_in[12];
  const float* bn2_m  = (const float*)d_in[13];
  const float* bn2_v  = (const float*)d_in[14];
  const float* pb_w   = (const float*)d_in[15];
  const float* pb_b   = (const float*)d_in[16];
  const float* fn_g   = (const float*)d_in[17];
  const float* fn_b   = (const float*)d_in[18];
  const float* mn_g   = (const float*)d_in[19];
  const float* mn_b   = (const float*)d_in[20];
  const float* protos = (const float*)d_in[21];

  float* ws  = (float*)d_ws;
  float* out = (float*)d_out;

  float* buf   = ws + WS_BUF;
  short* wpk_h = (short*)(ws + WS_WPK);
  short* wpk_l = wpk_h + 9 * 8 * 256 * 36;
  float* paT  = ws + WS_PAT;
  float* pbT  = ws + WS_PBT;
  float* Pn   = ws + WS_PN;
  float* PnT  = ws + WS_PNT;
  float* Tarr = ws + WS_T;
  float* farr = ws + WS_F;
  float* aarr = ws + WS_A;
  int*   ncnt = (int*)(ws + WS_NCNT);
  int*   corr = (int*)(ws + WS_CORR);
  int*   key  = (int*)(ws + WS_KEY);

  float* logits = out + O_LOG;

  // zero T[3*192] + f[48640] + a[3*192] + ncnt[192]  (contiguous region)
  hipMemsetAsync(ws + WS_T, 0, (size_t)(576 + 48640 + 576 + 192) * 4, stream);

  k_prep_protos<<<RP, 256, 0, stream>>>(protos, Pn, PnT);
  k_prep_wsplit<<<72, 256, 0, stream>>>(conv_w, wpk_h, wpk_l);
  k_transpose_w<<<512, 256, 0, stream>>>(pa_w, pb_w, paT, pbT);
  k_conv_mfma<<<dim3(1024, 2), 256, 0, stream>>>(x, wpk_h, wpk_l, conv_b,
                                                 bn1_s, bn1_b, bn1_m, bn1_v, buf);
  k_mlp<0><<<2048, 256, 0, stream>>>(buf, paT, pa_b, bn2_s, bn2_b, bn2_m, bn2_v);
  k_mlp<1><<<2048, 256, 0, stream>>>(buf, pbT, pb_b, fn_g, fn_b, nullptr, nullptr);
  k_masks<<<dim3(2048, 3), 256, 0, stream>>>(buf, PnT, logits);
  k_out<<<2048, 256, 0, stream>>>(logits, gt, mn_g, mn_b, out, corr);
  k_sink_sum<<<512, 256, 0, stream>>>(logits, gt, Tarr + 0,   nullptr);
  k_calc_a<<<1, 256, 0, stream>>>(Tarr + 0,   aarr + 0);
  k_sink_sum<<<512, 256, 0, stream>>>(logits, gt, Tarr + 192, aarr + 0);
  k_calc_a<<<1, 256, 0, stream>>>(Tarr + 192, aarr + 192);
  k_sink_sum<<<512, 256, 0, stream>>>(logits, gt, Tarr + 384, aarr + 192);
  k_calc_a<<<1, 256, 0, stream>>>(Tarr + 384, aarr + 384);
  k_final<<<512, 256, 0, stream>>>(logits, gt, aarr + 384, gu, corr, out + O_TGT, key, ncnt);
  k_accum_f<<<2048, 256, 0, stream>>>(key, buf, farr);
  k_update<<<190, 256, 0, stream>>>(Pn, farr, ncnt, out + O_PROTO);

  (void)in_sizes; (void)n_in; (void)out_size; (void)ws_size;
}

// Round 4
// 1584.586 us; speedup vs baseline: 2.1078x; 1.3144x over previous
//
#include <hip/hip_runtime.h>
#include <cstddef>
#include <cstdint>

// ---------------- problem constants ----------------
#define BB   4
#define CC   256
#define HHh  128
#define WWi  256
#define HW   32768      // H*W
#define CHW  8388608    // C*H*W
#define NN   131072     // B*H*W
#define KK   19
#define MMp  10
#define RR   190        // K*M
#define RP   192

// ---------------- output offsets (floats) ----------------
#define O_LOG   2490368     // out_seg size = 4*19*128*256
#define O_TGT   27394048
#define O_PROTO 27525120

// ---------------- ws offsets (floats) ----------------
#define WS_BUF   0           // 33,554,432 : y -> z1 -> _c (in-place, [b][c][h][w] layout)
#define WS_WPK   33554432    // 663,552 floats: wpk_h + wpk_l, each 9*8*256*36 shorts
#define WS_PAT   34217984    // 65,536 : pa_w^T [c][o]
#define WS_PBT   34283520    // 65,536 : pb_w^T [c][o]
#define WS_PN    34349056    // 48,640 : normalized protos [190][256]
#define WS_PNT   34397696    // 49,152 : PnT [256][192]
#define WS_T     34446848    // 3*192 sinkhorn sums
#define WS_F     34447424    // 48,640 : f accumulator
#define WS_A     34496064    // 3*192 sinkhorn row scales
#define WS_NCNT  34496640    // 192 int
#define WS_CORR  34496832    // 131,072 int
#define WS_KEY   34627904    // 131,072 int
// end = 34,758,976 floats = 139.0 MB (same as round-3 footprint, proven to fit)

typedef __attribute__((ext_vector_type(8))) short bf16x8;
typedef __attribute__((ext_vector_type(4))) short s16x4;
typedef __attribute__((ext_vector_type(4))) float f32x4;

// split fp32 v into bf16 hi (truncate) + bf16 lo (truncate of residual)
__device__ __forceinline__ void split2pack(float v0, float v1, unsigned& hp, unsigned& lp) {
  unsigned u0 = __float_as_uint(v0), u1 = __float_as_uint(v1);
  unsigned h0 = u0 & 0xffff0000u, h1 = u1 & 0xffff0000u;
  float r0 = v0 - __uint_as_float(h0);
  float r1 = v1 - __uint_as_float(h1);
  hp = (h0 >> 16) | h1;
  lp = (__float_as_uint(r0) >> 16) | (__float_as_uint(r1) & 0xffff0000u);
}

__device__ __forceinline__ void split1(float v, short& h, short& l) {
  unsigned u = __float_as_uint(v);
  unsigned hm = u & 0xffff0000u;
  float r = v - __uint_as_float(hm);
  h = (short)(hm >> 16);
  l = (short)(__float_as_uint(r) >> 16);
}

__device__ __forceinline__ bf16x8 ldfrag(const short* p) {
  union { bf16x8 v; s16x4 q[2]; } u;
  u.q[0] = *(const s16x4*)p;
  u.q[1] = *(const s16x4*)(p + 4);
  return u.v;
}

// ============ prototype normalize ============
__global__ __launch_bounds__(256) void k_prep_protos(const float* __restrict__ protos,
                                                     float* __restrict__ Pn,
                                                     float* __restrict__ PnT) {
  int r = blockIdx.x, d = threadIdx.x;
  if (r >= RR) { PnT[d * RP + r] = 0.f; return; }  // zero pad cols 190,191
  float v = protos[r * 256 + d];
  __shared__ float red[256];
  red[d] = v * v;
  __syncthreads();
  #pragma unroll
  for (int s = 128; s > 0; s >>= 1) {
    if (d < s) red[d] += red[d + s];
    __syncthreads();
  }
  float inv = 1.f / fmaxf(sqrtf(red[0]), 1e-12f);
  float pv = v * inv;
  Pn[r * 256 + d] = pv;
  PnT[d * RP + r] = pv;
}

// ============ conv weight split-pack prepass ============
// wpk[t9][icb][oc][36] bf16 (32 real ic + 4 pad), h and l arrays.
__global__ __launch_bounds__(256) void k_prep_wsplit(const float* __restrict__ conv_w,
                                                     short* __restrict__ wpk_h,
                                                     short* __restrict__ wpk_l) {
  int blk = blockIdx.x;             // t9*8 + icb
  int t9 = blk >> 3, icb = blk & 7;
  int oc = threadIdx.x;
  short* dh = wpk_h + ((size_t)blk * 256 + oc) * 36;
  short* dl = wpk_l + ((size_t)blk * 256 + oc) * 36;
  #pragma unroll 4
  for (int i = 0; i < 32; i++) {
    float v = conv_w[((size_t)oc * 256 + icb * 32 + i) * 9 + t9];
    short h, l;
    split1(v, h, l);
    dh[i] = h; dl[i] = l;
  }
  #pragma unroll
  for (int i = 32; i < 36; i++) { dh[i] = 0; dl[i] = 0; }
}

// ============ 1x1 weight transposes ============
__global__ __launch_bounds__(256) void k_transpose_w(const float* __restrict__ pa_w,
                                                     const float* __restrict__ pb_w,
                                                     float* __restrict__ paT,
                                                     float* __restrict__ pbT) {
  int blk = blockIdx.x, t = threadIdx.x;
  if (blk < 256) {
    paT[blk * 256 + t] = pa_w[t * 256 + blk];
  } else {
    int c = blk - 256;
    pbT[c * 256 + t] = pb_w[t * 256 + c];
  }
}

// ============ conv3x3 + bias + bn1 + relu : bf16x2-split MFMA ============
// grid 1024: bid = (b<<8) | (th<<4) | tw. Block tile = 8h x 16w px, ALL 256 oc.
// 4 waves = 2M x 2N; wave tile 64px(4 h-rows) x 128oc = 4x8 frags, K-step 32.
__global__ __launch_bounds__(256, 2) void k_conv_mfma(const float* __restrict__ x,
                                                      const short* __restrict__ wpk_h,
                                                      const short* __restrict__ wpk_l,
                                                      const float* __restrict__ conv_b,
                                                      const float* __restrict__ bn_s,
                                                      const float* __restrict__ bn_b,
                                                      const float* __restrict__ bn_m,
                                                      const float* __restrict__ bn_v,
                                                      float* __restrict__ y) {
  int bid = blockIdx.x;
  int tw = bid & 15, th = (bid >> 4) & 15, b = bid >> 8;
  int h0 = th * 8, w0 = tw * 16;
  int tid = threadIdx.x;
  int lane = tid & 63, wv = tid >> 6;
  int wm = wv & 1, wn = wv >> 1;
  int l15 = lane & 15, l4 = lane >> 4;

  __shared__ short xt_h[10 * 18 * 36];   // [row 10][ww 18][ic 32+4pad]
  __shared__ short xt_l[10 * 18 * 36];
  __shared__ short wt_h[256 * 36];       // [oc 256][ic 32+4pad]
  __shared__ short wt_l[256 * 36];

  f32x4 acc[4][8];
  #pragma unroll
  for (int i = 0; i < 4; i++)
    #pragma unroll
    for (int j = 0; j < 8; j++) acc[i][j] = (f32x4){0.f, 0.f, 0.f, 0.f};

  const float* xb = x + (size_t)b * CHW;

  #pragma unroll 1
  for (int ic0 = 0; ic0 < 256; ic0 += 32) {
    int icb = ic0 >> 5;
    // ---- stage A: 10 rows x 18 ww x 16 ic-pairs, split h/l. ww fastest (coalesce). ----
    #pragma unroll 1
    for (int idx = tid; idx < 2880; idx += 256) {
      int ww = idx % 18;
      int t  = idx / 18;       // 0..159
      int r  = t % 10;
      int ip = t / 10;         // 0..15
      int hh = h0 - 1 + r, wg = w0 - 1 + ww;
      float v0 = 0.f, v1 = 0.f;
      if ((unsigned)hh < 128u && (unsigned)wg < 256u) {
        const float* px = xb + (size_t)(ic0 + 2 * ip) * HW + hh * WWi + wg;
        v0 = px[0]; v1 = px[HW];
      }
      unsigned hp, lp;
      split2pack(v0, v1, hp, lp);
      int off = (r * 18 + ww) * 36 + 2 * ip;
      *(unsigned*)&xt_h[off] = hp;
      *(unsigned*)&xt_l[off] = lp;
    }
    // ---- 9 taps ----
    #pragma unroll 1
    for (int kh = 0; kh < 3; ++kh) {
      #pragma unroll 1
      for (int kw = 0; kw < 3; ++kw) {
        int t9 = kh * 3 + kw;
        {   // stage B: linear copy 256 oc x 36 shorts (h and l) = 4608 dwords each
          const unsigned* sh_ = (const unsigned*)(wpk_h + ((size_t)(t9 * 8 + icb) * 256) * 36);
          const unsigned* sl_ = (const unsigned*)(wpk_l + ((size_t)(t9 * 8 + icb) * 256) * 36);
          unsigned* dh_ = (unsigned*)wt_h;
          unsigned* dl_ = (unsigned*)wt_l;
          #pragma unroll 1
          for (int idx = tid; idx < 4608; idx += 256) { dh_[idx] = sh_[idx]; dl_[idx] = sl_[idx]; }
        }
        __syncthreads();
        bf16x8 ah[4], al[4];
        #pragma unroll
        for (int mf = 0; mf < 4; ++mf) {
          int off = ((wm * 4 + mf + kh) * 18 + l15 + kw) * 36 + l4 * 8;
          ah[mf] = ldfrag(xt_h + off);
          al[mf] = ldfrag(xt_l + off);
        }
        #pragma unroll
        for (int nf = 0; nf < 8; ++nf) {
          int off = (wn * 128 + nf * 16 + l15) * 36 + l4 * 8;
          bf16x8 bh = ldfrag(wt_h + off);
          bf16x8 bl = ldfrag(wt_l + off);
          #pragma unroll
          for (int mf = 0; mf < 4; ++mf) {
            acc[mf][nf] = __builtin_amdgcn_mfma_f32_16x16x32_bf16(ah[mf], bh, acc[mf][nf], 0, 0, 0);
            acc[mf][nf] = __builtin_amdgcn_mfma_f32_16x16x32_bf16(ah[mf], bl, acc[mf][nf], 0, 0, 0);
            acc[mf][nf] = __builtin_amdgcn_mfma_f32_16x16x32_bf16(al[mf], bh, acc[mf][nf], 0, 0, 0);
          }
        }
        __syncthreads();
      }
    }
  }
  // ---- epilogue: BN + ReLU, store f32x4 along w ----
  float* yb = y + (size_t)b * CHW;
  #pragma unroll
  for (int nf = 0; nf < 8; ++nf) {
    int oc = wn * 128 + nf * 16 + l15;
    float sc = bn_s[oc] / sqrtf(bn_v[oc] + 1e-5f);
    float sh = (conv_b[oc] - bn_m[oc]) * sc + bn_b[oc];
    #pragma unroll
    for (int mf = 0; mf < 4; ++mf) {
      int hr = h0 + wm * 4 + mf;
      int w  = w0 + l4 * 4;
      float4 o;
      o.x = fmaxf(acc[mf][nf][0] * sc + sh, 0.f);
      o.y = fmaxf(acc[mf][nf][1] * sc + sh, 0.f);
      o.z = fmaxf(acc[mf][nf][2] * sc + sh, 0.f);
      o.w = fmaxf(acc[mf][nf][3] * sc + sh, 0.f);
      *(float4*)&yb[(size_t)oc * HW + hr * WWi + w] = o;
    }
  }
}

// ============ 1x1-conv stages, in-place (full 256 oc per 64-px tile) ============
// MODE 0: z1 = relu(bn2(pa_w@y + pa_b));  p0..p3 = bn2 s,b,m,v
// MODE 1: _c = l2n(ln(l2n(pb_w@z1 + pb_b), fn_g, fn_b)); p0,p1 = fn_g,fn_b
template <int MODE>
__global__ __launch_bounds__(256) void k_mlp(float* __restrict__ buf,
                                             const float* __restrict__ wTr,
                                             const float* __restrict__ bias,
                                             const float* __restrict__ p0,
                                             const float* __restrict__ p1,
                                             const float* __restrict__ p2,
                                             const float* __restrict__ p3) {
  int bid = blockIdx.x;
  int b = bid >> 9, hw0 = (bid & 511) * 64;
  int tid = threadIdx.x, tx = tid & 15, ty = tid >> 4;
  __shared__ float xsS[8][68];
  __shared__ float wsS[8][256];
  __shared__ float redS[2][16][16][4];
  float acc[16][4];
  #pragma unroll
  for (int o = 0; o < 16; o++)
    #pragma unroll
    for (int i = 0; i < 4; i++) acc[o][i] = 0.f;

  float* src = buf + (size_t)b * CHW + hw0;
  for (int c0 = 0; c0 < 256; c0 += 8) {
    for (int idx = tid; idx < 512; idx += 256) {
      int kc = idx >> 6, px = idx & 63;
      xsS[kc][px] = src[(size_t)(c0 + kc) * HW + px];
    }
    for (int idx = tid; idx < 2048; idx += 256) {
      int kc = idx >> 8, oc = idx & 255;
      wsS[kc][oc] = wTr[(c0 + kc) * 256 + oc];
    }
    __syncthreads();
    #pragma unroll
    for (int kc = 0; kc < 8; kc++) {
      float4 xv = *(const float4*)&xsS[kc][tx * 4];
      float xr[4] = {xv.x, xv.y, xv.z, xv.w};
      #pragma unroll
      for (int q = 0; q < 4; q++) {
        float4 wv = *(const float4*)&wsS[kc][ty * 16 + q * 4];
        float wr[4] = {wv.x, wv.y, wv.z, wv.w};
        #pragma unroll
        for (int jo = 0; jo < 4; jo++)
          #pragma unroll
          for (int i = 0; i < 4; i++)
            acc[q * 4 + jo][i] = fmaf(wr[jo], xr[i], acc[q * 4 + jo][i]);
      }
    }
    __syncthreads();
  }

  if (MODE == 0) {
    #pragma unroll
    for (int o = 0; o < 16; o++) {
      int oc = ty * 16 + o;
      float sc = p0[oc] / sqrtf(p3[oc] + 1e-5f);
      float sh = (bias[oc] - p2[oc]) * sc + p1[oc];
      float4 ov;
      ov.x = fmaxf(acc[o][0] * sc + sh, 0.f);
      ov.y = fmaxf(acc[o][1] * sc + sh, 0.f);
      ov.z = fmaxf(acc[o][2] * sc + sh, 0.f);
      ov.w = fmaxf(acc[o][3] * sc + sh, 0.f);
      *(float4*)&buf[(size_t)b * CHW + (size_t)oc * HW + hw0 + tx * 4] = ov;
    }
  } else {
    float s1[4] = {0, 0, 0, 0}, s2[4] = {0, 0, 0, 0};
    #pragma unroll
    for (int o = 0; o < 16; o++) {
      float bz = bias[ty * 16 + o];
      #pragma unroll
      for (int i = 0; i < 4; i++) {
        float z = acc[o][i] + bz;
        acc[o][i] = z;
        s1[i] += z;
        s2[i] += z * z;
      }
    }
    #pragma unroll
    for (int i = 0; i < 4; i++) { redS[0][ty][tx][i] = s1[i]; redS[1][ty][tx][i] = s2[i]; }
    __syncthreads();
    #pragma unroll
    for (int s = 8; s > 0; s >>= 1) {
      if (ty < s) {
        #pragma unroll
        for (int i = 0; i < 4; i++) {
          redS[0][ty][tx][i] += redS[0][ty + s][tx][i];
          redS[1][ty][tx][i] += redS[1][ty + s][tx][i];
        }
      }
      __syncthreads();
    }
    float invn[4], muu[4], rq[4];
    #pragma unroll
    for (int i = 0; i < 4; i++) {
      float S1 = redS[0][0][tx][i], S2 = redS[1][0][tx][i];
      float iv = 1.f / fmaxf(sqrtf(S2), 1e-12f);
      float mu = S1 * iv * (1.f / 256.f);
      float eu2 = S2 * iv * iv * (1.f / 256.f);
      float var = fmaxf(eu2 - mu * mu, 0.f);
      invn[i] = iv; muu[i] = mu; rq[i] = 1.f / sqrtf(var + 1e-5f);
    }
    __syncthreads();
    float s3[4] = {0, 0, 0, 0};
    #pragma unroll
    for (int o = 0; o < 16; o++) {
      int oc = ty * 16 + o;
      float g = p0[oc], bt = p1[oc];
      #pragma unroll
      for (int i = 0; i < 4; i++) {
        float v = (acc[o][i] * invn[i] - muu[i]) * rq[i] * g + bt;
        acc[o][i] = v;
        s3[i] += v * v;
      }
    }
    #pragma unroll
    for (int i = 0; i < 4; i++) redS[0][ty][tx][i] = s3[i];
    __syncthreads();
    #pragma unroll
    for (int s = 8; s > 0; s >>= 1) {
      if (ty < s) {
        #pragma unroll
        for (int i = 0; i < 4; i++) redS[0][ty][tx][i] += redS[0][ty + s][tx][i];
      }
      __syncthreads();
    }
    float cinv[4];
    #pragma unroll
    for (int i = 0; i < 4; i++)
      cinv[i] = 1.f / fmaxf(sqrtf(redS[0][0][tx][i]), 1e-12f);
    #pragma unroll
    for (int o = 0; o < 16; o++) {
      int oc = ty * 16 + o;
      float4 ov;
      ov.x = acc[o][0] * cinv[0];
      ov.y = acc[o][1] * cinv[1];
      ov.z = acc[o][2] * cinv[2];
      ov.w = acc[o][3] * cinv[3];
      *(float4*)&buf[(size_t)b * CHW + (size_t)oc * HW + hw0 + tx * 4] = ov;
    }
  }
}

// ============ masks / proto_logits GEMM: _c[64px] x PnT -> logits[n][190] ============
__global__ __launch_bounds__(256) void k_masks(const float* __restrict__ cbuf,
                                               const float* __restrict__ PnT,
                                               float* __restrict__ logits) {
  int pt = blockIdx.x;
  int b = pt >> 9, hw0 = (pt & 511) * 64;
  int r0 = blockIdx.y * 64;
  int tid = threadIdx.x, tx = tid & 15, ty = tid >> 4;
  __shared__ float xsS[16][68];
  __shared__ float wsS[16][64];
  float acc[4][4];
  #pragma unroll
  for (int j = 0; j < 4; j++)
    #pragma unroll
    for (int i = 0; i < 4; i++) acc[j][i] = 0.f;

  const float* src = cbuf + (size_t)b * CHW + hw0;
  for (int c0 = 0; c0 < 256; c0 += 16) {
    for (int idx = tid; idx < 1024; idx += 256) {
      int kc = idx >> 6, px = idx & 63;
      xsS[kc][px] = src[(size_t)(c0 + kc) * HW + px];
    }
    for (int idx = tid; idx < 1024; idx += 256) {
      int kc = idx >> 6, r = idx & 63;
      wsS[kc][r] = PnT[(c0 + kc) * RP + r0 + r];
    }
    __syncthreads();
    #pragma unroll
    for (int kc = 0; kc < 16; kc++) {
      float4 xv = *(const float4*)&xsS[kc][tx * 4];
      float4 wv = *(const float4*)&wsS[kc][ty * 4];
      float xr[4] = {xv.x, xv.y, xv.z, xv.w};
      float wr[4] = {wv.x, wv.y, wv.z, wv.w};
      #pragma unroll
      for (int j = 0; j < 4; j++)
        #pragma unroll
        for (int i = 0; i < 4; i++)
          acc[j][i] = fmaf(wr[j], xr[i], acc[j][i]);
    }
    __syncthreads();
  }
  int n0 = b * HW + hw0 + tx * 4;
  #pragma unroll
  for (int j = 0; j < 4; j++) {
    int r = r0 + ty * 4 + j;
    if (r < RR) {
      #pragma unroll
      for (int i = 0; i < 4; i++)
        logits[(size_t)(n0 + i) * RR + r] = acc[j][i];
    }
  }
}

// ============ out_seg = LN_k(max_j masks) + pred/correct ============
__global__ __launch_bounds__(256) void k_out(const float* __restrict__ logits,
                                             const int* __restrict__ gt,
                                             const float* __restrict__ mn_g,
                                             const float* __restrict__ mn_b,
                                             float* __restrict__ out_seg,
                                             int* __restrict__ corr) {
  __shared__ float lds[64][193];
  int n0 = blockIdx.x * 64;
  int tid = threadIdx.x;
  for (int idx = tid; idx < 64 * RR; idx += 256) {
    int rr = idx / RR, cc = idx - rr * RR;
    lds[rr][cc] = logits[(size_t)n0 * RR + idx];
  }
  __syncthreads();
  if (tid < 64) {
    int n = n0 + tid;
    float mx[KK];
    float S1 = 0.f, S2 = 0.f;
    #pragma unroll
    for (int k = 0; k < KK; k++) {
      float m_ = lds[tid][k * 10];
      #pragma unroll
      for (int j = 1; j < 10; j++) m_ = fmaxf(m_, lds[tid][k * 10 + j]);
      mx[k] = m_;
      S1 += m_;
      S2 += m_ * m_;
    }
    float mu = S1 * (1.f / 19.f);
    float var = fmaxf(S2 * (1.f / 19.f) - mu * mu, 0.f);
    float inv = 1.f / sqrtf(var + 1e-5f);
    int b = n >> 15, hw = n & 32767;
    float best = -3.4e38f;
    int pred = 0;
    #pragma unroll
    for (int k = 0; k < KK; k++) {
      float o = (mx[k] - mu) * inv * mn_g[k] + mn_b[k];
      out_seg[(size_t)b * 622592 + (size_t)k * 32768 + hw] = o;
      if (o > best) { best = o; pred = k; }
    }
    corr[n] = (gt[n] == pred) ? 1 : 0;
  }
}

// ============ sinkhorn reduction pass: T[k*10+j] += E * b(aprev) ============
__global__ __launch_bounds__(256) void k_sink_sum(const float* __restrict__ logits,
                                                  const int* __restrict__ gt,
                                                  float* __restrict__ Tout,
                                                  const float* __restrict__ aprev) {
  __shared__ float tl[RP];
  int tid = threadIdx.x;
  if (tid < RP) tl[tid] = 0.f;
  __syncthreads();
  int n = blockIdx.x * 256 + tid;
  int k = gt[n];
  const float* lp = logits + (size_t)n * RR + k * 10;
  float e[10];
  #pragma unroll
  for (int j = 0; j < 10; j++) e[j] = expf(lp[j] * 20.0f);
  float bfac = 1.f;
  if (aprev != nullptr) {
    float den = 0.f;
    #pragma unroll
    for (int j = 0; j < 10; j++) den += e[j] * aprev[k * 10 + j];
    bfac = 1.f / fmaxf(den, 1e-30f);
  }
  #pragma unroll
  for (int j = 0; j < 10; j++) atomicAdd(&tl[k * 10 + j], e[j] * bfac);
  __syncthreads();
  if (tid < RR) atomicAdd(&Tout[tid], tl[tid]);
}

__global__ __launch_bounds__(256) void k_calc_a(const float* __restrict__ T,
                                                float* __restrict__ a) {
  int t = threadIdx.x;
  if (t < RR) a[t] = 1.f / (10.f * fmaxf(T[t], 1e-12f));
  else if (t < RP) a[t] = 0.f;
}

// ============ final sinkhorn pass: proto_target, gumbel-hard key, n_cnt ============
__global__ __launch_bounds__(256) void k_final(const float* __restrict__ logits,
                                               const int* __restrict__ gt,
                                               const float* __restrict__ a3,
                                               const float* __restrict__ gu,
                                               const int* __restrict__ corr,
                                               float* __restrict__ tgt,
                                               int* __restrict__ key,
                                               int* __restrict__ ncnt) {
  int n = blockIdx.x * 256 + threadIdx.x;
  int k = gt[n];
  const float* lp = logits + (size_t)n * RR + k * 10;
  float w[10];
  float den = 0.f, bestw = -1.f;
  int idx = 0;
  #pragma unroll
  for (int j = 0; j < 10; j++) {
    w[j] = expf(lp[j] * 20.0f) * a3[k * 10 + j];
    den += w[j];
    if (w[j] > bestw) { bestw = w[j]; idx = j; }
  }
  tgt[n] = (float)(idx + 10 * k);
  float dinv = 1.f / fmaxf(den, 1e-30f);
  const float* gp = gu + ((size_t)k * NN + n) * 10;
  float bestq = -3.4e38f;
  int jh = 0;
  #pragma unroll
  for (int j = 0; j < 10; j++) {
    float g = -logf(-logf(gp[j] + 1e-20f) + 1e-20f);
    float q = w[j] * dinv + g;
    if (q > bestq) { bestq = q; jh = j; }
  }
  int kv = -1;
  if (corr[n]) {
    kv = k * 10 + jh;
    atomicAdd(&ncnt[kv], 1);
  }
  key[n] = kv;
}

// ============ f[k,j,:] += _c[n,:] over counted samples ============
__global__ __launch_bounds__(256) void k_accum_f(const int* __restrict__ key,
                                                 const float* __restrict__ cbuf,
                                                 float* __restrict__ f) {
  __shared__ int ks[64];
  int n0 = blockIdx.x * 64;
  int tid = threadIdx.x;
  if (tid < 64) ks[tid] = key[n0 + tid];
  __syncthreads();
  for (int s = 0; s < 64; s++) {
    int kv = ks[s];
    if (kv >= 0) {
      int n = n0 + s;
      int b = n >> 15, hw = n & 32767;
      atomicAdd(&f[kv * 256 + tid], cbuf[(size_t)b * CHW + (size_t)tid * HW + hw]);
    }
  }
}

// ============ prototype EMA update + renormalize ============
__global__ __launch_bounds__(256) void k_update(const float* __restrict__ Pn,
                                                const float* __restrict__ f,
                                                const int* __restrict__ ncnt,
                                                float* __restrict__ outP) {
  int r = blockIdx.x, d = threadIdx.x;
  int k = r / 10;
  __shared__ float red[256];
  __shared__ int hasS;
  if (d == 0) {
    int s = 0;
    for (int j = 0; j < 10; j++) s += ncnt[k * 10 + j];
    hasS = s;
  }
  __syncthreads();
  bool upd = (ncnt[r] != 0) && (hasS > 0);
  float fv = f[r * 256 + d];
  red[d] = fv * fv;
  __syncthreads();
  #pragma unroll
  for (int s = 128; s > 0; s >>= 1) {
    if (d < s) red[d] += red[d + s];
    __syncthreads();
  }
  float fn2 = red[0];
  __syncthreads();
  float fl = fv / fmaxf(sqrtf(fn2), 1e-12f);
  float p = Pn[r * 256 + d];
  float nv = upd ? (0.999f * p + 0.001f * fl) : p;
  red[d] = nv * nv;
  __syncthreads();
  #pragma unroll
  for (int s = 128; s > 0; s >>= 1) {
    if (d < s) red[d] += red[d + s];
    __syncthreads();
  }
  outP[r * 256 + d] = nv / fmaxf(sqrtf(red[0]), 1e-12f);
}

// ============ launch ============
extern "C" void kernel_launch(void* const* d_in, const int* in_sizes, int n_in,
                              void* d_out, int out_size, void* d_ws, size_t ws_size,
                              hipStream_t stream) {
  const float* x      = (const float*)d_in[0];
  const int*   gt     = (const int*)  d_in[1];
  const float* gu     = (const float*)d_in[2];
  const float* conv_w = (const float*)d_in[3];
  const float* conv_b = (const float*)d_in[4];
  const float* bn1_s  = (const float*)d_in[5];
  const float* bn1_b  = (const float*)d_in[6];
  const float* bn1_m  = (const float*)d_in[7];
  const float* bn1_v  = (const float*)d_in[8];
  const float* pa_w   = (const float*)d_in[9];
  const float* pa_b   = (const float*)d_in[10];
  const float* bn2_s  = (const float*)d_in[11];
  const float* bn2_b  = (const float*)d_in[12];
  const float* bn2_m  = (const float*)d_in[13];
  const float* bn2_v  = (const float*)d_in[14];
  const float* pb_w   = (const float*)d_in[15];
  const float* pb_b   = (const float*)d_in[16];
  const float* fn_g   = (const float*)d_in[17];
  const float* fn_b   = (const float*)d_in[18];
  const float* mn_g   = (const float*)d_in[19];
  const float* mn_b   = (const float*)d_in[20];
  const float* protos = (const float*)d_in[21];

  float* ws  = (float*)d_ws;
  float* out = (float*)d_out;

  float* buf   = ws + WS_BUF;
  short* wpk_h = (short*)(ws + WS_WPK);
  short* wpk_l = wpk_h + 9 * 8 * 256 * 36;
  float* paT  = ws + WS_PAT;
  float* pbT  = ws + WS_PBT;
  float* Pn   = ws + WS_PN;
  float* PnT  = ws + WS_PNT;
  float* Tarr = ws + WS_T;
  float* farr = ws + WS_F;
  float* aarr = ws + WS_A;
  int*   ncnt = (int*)(ws + WS_NCNT);
  int*   corr = (int*)(ws + WS_CORR);
  int*   key  = (int*)(ws + WS_KEY);

  float* logits = out + O_LOG;

  // zero T[3*192] + f[48640] + a[3*192] + ncnt[192]  (contiguous region)
  hipMemsetAsync(ws + WS_T, 0, (size_t)(576 + 48640 + 576 + 192) * 4, stream);

  k_prep_protos<<<RP, 256, 0, stream>>>(protos, Pn, PnT);
  k_prep_wsplit<<<72, 256, 0, stream>>>(conv_w, wpk_h, wpk_l);
  k_transpose_w<<<512, 256, 0, stream>>>(pa_w, pb_w, paT, pbT);
  k_conv_mfma<<<1024, 256, 0, stream>>>(x, wpk_h, wpk_l, conv_b,
                                        bn1_s, bn1_b, bn1_m, bn1_v, buf);
  k_mlp<0><<<2048, 256, 0, stream>>>(buf, paT, pa_b, bn2_s, bn2_b, bn2_m, bn2_v);
  k_mlp<1><<<2048, 256, 0, stream>>>(buf, pbT, pb_b, fn_g, fn_b, nullptr, nullptr);
  k_masks<<<dim3(2048, 3), 256, 0, stream>>>(buf, PnT, logits);
  k_out<<<2048, 256, 0, stream>>>(logits, gt, mn_g, mn_b, out, corr);
  k_sink_sum<<<512, 256, 0, stream>>>(logits, gt, Tarr + 0,   nullptr);
  k_calc_a<<<1, 256, 0, stream>>>(Tarr + 0,   aarr + 0);
  k_sink_sum<<<512, 256, 0, stream>>>(logits, gt, Tarr + 192, aarr + 0);
  k_calc_a<<<1, 256, 0, stream>>>(Tarr + 192, aarr + 192);
  k_sink_sum<<<512, 256, 0, stream>>>(logits, gt, Tarr + 384, aarr + 192);
  k_calc_a<<<1, 256, 0, stream>>>(Tarr + 384, aarr + 384);
  k_final<<<512, 256, 0, stream>>>(logits, gt, aarr + 384, gu, corr, out + O_TGT, key, ncnt);
  k_accum_f<<<2048, 256, 0, stream>>>(key, buf, farr);
  k_update<<<190, 256, 0, stream>>>(Pn, farr, ncnt, out + O_PROTO);

  (void)in_sizes; (void)n_in; (void)out_size; (void)ws_size;
}